// Round 4
// baseline (335.078 us; speedup 1.0000x reference)
//
#include <hip/hip_runtime.h>

#define E_EDGES 1000000
#define NNODES  100000
#define HID     128
#define NG      31250     // 32-edge groups, exact
#define NBLK    768       // 3 blocks/CU x 256 CUs

typedef float f32x4 __attribute__((ext_vector_type(4)));
typedef short s16x8 __attribute__((ext_vector_type(8)));

// float -> bf16, round-to-nearest-even (inputs are finite)
__device__ __forceinline__ unsigned short f2bf(float f) {
  unsigned int u = __float_as_uint(f);
  u += 0x7FFFu + ((u >> 16) & 1u);
  return (unsigned short)(u >> 16);
}

__device__ __forceinline__ int4 pack8(float4 a, float4 b) {
  int4 v;
  v.x = (int)((unsigned)f2bf(a.x) | ((unsigned)f2bf(a.y) << 16));
  v.y = (int)((unsigned)f2bf(a.z) | ((unsigned)f2bf(a.w) << 16));
  v.z = (int)((unsigned)f2bf(b.x) | ((unsigned)f2bf(b.y) << 16));
  v.w = (int)((unsigned)f2bf(b.z) | ((unsigned)f2bf(b.w) << 16));
  return v;
}

// x fp32 [NNODES*HID] -> bf16 in ws.
__global__ void cast_x_kernel(const float* __restrict__ x,
                              unsigned short* __restrict__ xb) {
  int i = blockIdx.x * blockDim.x + threadIdx.x;
  const float4* p = (const float4*)x;
  float4 a = p[2 * i];
  float4 b = p[2 * i + 1];
  int4 v = pack8(a, b);
  ((int4*)xb)[i] = v;
}

// XOR-swizzled LDS layouts. Chunk = 16B = 8 bf16 of K.
__device__ __forceinline__ int EF(int t, int m, int c) {
  return t * 8192 + m * 512 + ((((c ^ m) & 7) | (c & 24)) << 4);
}
__device__ __forceinline__ int H1(int t, int m, int c2) {
  return t * 4096 + m * 256 + ((((c2 ^ m) & 7) | (c2 & 8)) << 4);
}

// 256 threads = 4 waves. ONE barrier per 32-edge group; cross-group software
// pipeline: iteration i runs stage(g) | prefetch(g+1) | out(g-2) | L1(g) |
// L2(g-1) on double-buffered ef/h1/red. All phases in one barrier epoch touch
// disjoint buffers, so the scheduler interleaves MFMA/VALU/LDS/VMEM freely.
template <bool PRE>
__launch_bounds__(256, 3)
__global__ void edge_mlp_kernel(const unsigned short* __restrict__ xb,
                                const float* __restrict__ xf,
                                const int* __restrict__ ei,
                                const float* __restrict__ attr,
                                const float* __restrict__ W1,
                                const float* __restrict__ b1,
                                const float* __restrict__ W2,
                                const float* __restrict__ b2,
                                const float* __restrict__ W3,
                                const float* __restrict__ b3,
                                float* __restrict__ out) {
  __shared__ __align__(16) unsigned char ef[2][16384];   // 32 KB
  __shared__ __align__(16) unsigned char h1b[2][8192];   // 16 KB
  __shared__ float red[2][4][16];                        // 512 B

  const int tid  = threadIdx.x;
  const int w    = tid >> 6;
  const int lane = tid & 63;
  const int q    = lane >> 4;
  const int l15  = lane & 15;
  const int jrow = w * 4 + q;     // row handled by this lane's quad (gathers)

  // ---- layer-1 weight fragments: wave w owns output cols 32w..32w+31 ----
  s16x8 B1[2][8];
  float b1v[2], w1l[2];
#pragma unroll
  for (int th = 0; th < 2; ++th) {
    const int nc = (w * 2 + th) * 16 + l15;
#pragma unroll
    for (int s = 0; s < 8; ++s)
#pragma unroll
      for (int j = 0; j < 8; ++j)
        B1[th][s][j] = (short)f2bf(W1[(s * 32 + q * 8 + j) * HID + nc]);
    b1v[th] = b1[nc];
    w1l[th] = W1[256 * HID + nc];   // attr column (k=256)
  }
  // ---- layer-2: wave w -> tile (w>>1), output half (w&1) ----
  const int n2 = (w & 1) * 16 + l15;
  s16x8 B2[4];
#pragma unroll
  for (int s2 = 0; s2 < 4; ++s2)
#pragma unroll
    for (int j = 0; j < 8; ++j)
      B2[s2][j] = (short)f2bf(W2[(s2 * 32 + q * 8 + j) * 32 + n2]);
  const float b2v = b2[n2];
  const float w3v = W3[n2];
  const float b3v = b3[0];

  const int bx = blockIdx.x;
  int nd2[4];
  int4 pv[4];
  float4 pa[4], pb[4];
  f32x4 an[2] = {{0.f,0.f,0.f,0.f},{0.f,0.f,0.f,0.f}};

  // ---- prologue: gather group bx, ids for bx+NBLK, attr for bx ----
  {
    const int base = bx * 32;
#pragma unroll
    for (int gg = 0; gg < 4; ++gg) {
      const int node = ei[(gg >> 1) * E_EDGES + base + (gg & 1) * 16 + jrow];
      if constexpr (PRE) {
        pv[gg] = *(const int4*)(xb + (size_t)node * HID + l15 * 8);
      } else {
        const float4* s = (const float4*)(xf + (size_t)node * HID + l15 * 8);
        pa[gg] = s[0]; pb[gg] = s[1];
      }
    }
#pragma unroll
    for (int t = 0; t < 2; ++t)
      an[t] = *(const f32x4*)(attr + base + t * 16 + q * 4);
    const int g1 = bx + NBLK;
    if (g1 < NG) {
      const int base1 = g1 * 32;
#pragma unroll
      for (int gg = 0; gg < 4; ++gg)
        nd2[gg] = ei[(gg >> 1) * E_EDGES + base1 + (gg & 1) * 16 + jrow];
    }
  }

  const int last_i = (NG - 1 - bx) / NBLK + 2;   // two drain iterations
  for (int i = 0; i <= last_i; ++i) {
    const int g   = bx + i * NBLK;
    const int cur = i & 1;
    const int prv = cur ^ 1;

    // stage(g): deposit gathered rows into ef[cur]
    if (g < NG) {
#pragma unroll
      for (int gg = 0; gg < 4; ++gg) {
        int4 v;
        if constexpr (PRE) v = pv[gg];
        else               v = pack8(pa[gg], pb[gg]);
        const int c = (gg >> 1) * 16 + l15;     // side*16 + chunk
        *(int4*)(&ef[cur][0] + EF(gg & 1, jrow, c)) = v;
      }
    }
    __syncthreads();
    // epoch: ef[cur] readable; h1b[prv] (written last iter) readable;
    // red[cur] (written last iter) readable.

    // prefetch(g+NBLK): gathers from ids loaded last iter; ids two ahead
    const int g1 = g + NBLK;
    f32x4 anx[2] = {{0.f,0.f,0.f,0.f},{0.f,0.f,0.f,0.f}};
    if (g1 < NG) {
#pragma unroll
      for (int gg = 0; gg < 4; ++gg) {
        const int node = nd2[gg];
        if constexpr (PRE) {
          pv[gg] = *(const int4*)(xb + (size_t)node * HID + l15 * 8);
        } else {
          const float4* s = (const float4*)(xf + (size_t)node * HID + l15 * 8);
          pa[gg] = s[0]; pb[gg] = s[1];
        }
      }
      const int base1 = g1 * 32;
#pragma unroll
      for (int t = 0; t < 2; ++t)
        anx[t] = *(const f32x4*)(attr + base1 + t * 16 + q * 4);
      const int g2 = g1 + NBLK;
      if (g2 < NG) {
        const int base2 = g2 * 32;
#pragma unroll
        for (int gg = 0; gg < 4; ++gg)
          nd2[gg] = ei[(gg >> 1) * E_EDGES + base2 + (gg & 1) * 16 + jrow];
      }
    }

    // out(g-2*NBLK): sigmoid + store, reads red[cur] (written one epoch ago)
    const int go = g - 2 * NBLK;
    if (go >= 0 && tid < 32) {
      const int t = tid >> 4, m = tid & 15;
      const float s = red[cur][t * 2][m] + red[cur][t * 2 + 1][m] + b3v;
      out[go * 32 + tid] = 1.f / (1.f + __expf(-s));
    }

    // layer1(g): ef[cur] -> h1b[cur]
    if (g < NG) {
#pragma unroll
      for (int t = 0; t < 2; ++t) {
        f32x4 acc0 = {0.f, 0.f, 0.f, 0.f};
        f32x4 acc1 = {0.f, 0.f, 0.f, 0.f};
#pragma unroll
        for (int s = 0; s < 8; ++s) {
          const s16x8 A = *(const s16x8*)(&ef[cur][0] + EF(t, l15, s * 4 + q));
          acc0 = __builtin_amdgcn_mfma_f32_16x16x32_bf16(A, B1[0][s], acc0, 0, 0, 0);
          acc1 = __builtin_amdgcn_mfma_f32_16x16x32_bf16(A, B1[1][s], acc1, 0, 0, 0);
        }
#pragma unroll
        for (int th = 0; th < 2; ++th) {
          const f32x4 acc = th ? acc1 : acc0;
          const int n  = (w * 2 + th) * 16 + l15;
          const int c2 = n >> 3;
#pragma unroll
          for (int r = 0; r < 4; ++r) {
            const int m = q * 4 + r;           // D: row = quad*4+reg, col = lane&15
            float v = acc[r] + b1v[th] + an[t][r] * w1l[th];
            v = fmaxf(v, 0.f);
            *(unsigned short*)(&h1b[cur][0] + H1(t, m, c2) + (n & 7) * 2) = f2bf(v);
          }
        }
      }
    }

    // layer2(g-NBLK): h1b[prv] -> red[prv]
    const int gm = g - NBLK;
    if (gm >= 0 && gm < NG) {
      const int t = w >> 1;
      f32x4 acc = {0.f, 0.f, 0.f, 0.f};
#pragma unroll
      for (int s2 = 0; s2 < 4; ++s2) {
        const s16x8 A2 = *(const s16x8*)(&h1b[prv][0] + H1(t, l15, s2 * 4 + q));
        acc = __builtin_amdgcn_mfma_f32_16x16x32_bf16(A2, B2[s2], acc, 0, 0, 0);
      }
      float p[4];
#pragma unroll
      for (int r = 0; r < 4; ++r)
        p[r] = fmaxf(acc[r] + b2v, 0.f) * w3v;
#pragma unroll
      for (int off = 8; off >= 1; off >>= 1)
#pragma unroll
        for (int r = 0; r < 4; ++r)
          p[r] += __shfl_xor(p[r], off, 16);
      if (l15 == 0) {
#pragma unroll
        for (int r = 0; r < 4; ++r)
          red[prv][w][q * 4 + r] = p[r];
      }
    }

    an[0] = anx[0];
    an[1] = anx[1];
  }
}

extern "C" void kernel_launch(void* const* d_in, const int* in_sizes, int n_in,
                              void* d_out, int out_size, void* d_ws, size_t ws_size,
                              hipStream_t stream) {
  const float* x    = (const float*)d_in[0];
  const int*   ei   = (const int*)d_in[1];
  const float* attr = (const float*)d_in[2];
  const float* W1   = (const float*)d_in[3];
  const float* b1   = (const float*)d_in[4];
  const float* W2   = (const float*)d_in[5];
  const float* b2   = (const float*)d_in[6];
  const float* W3   = (const float*)d_in[7];
  const float* b3   = (const float*)d_in[8];
  float* out = (float*)d_out;

  const size_t need = (size_t)NNODES * HID * sizeof(unsigned short);  // 25.6 MB
  if (ws_size >= need) {
    unsigned short* xb = (unsigned short*)d_ws;
    cast_x_kernel<<<6250, 256, 0, stream>>>(x, xb);
    edge_mlp_kernel<true><<<NBLK, 256, 0, stream>>>(xb, x, ei, attr, W1, b1, W2, b2, W3, b3, out);
  } else {
    edge_mlp_kernel<false><<<NBLK, 256, 0, stream>>>(nullptr, x, ei, attr, W1, b1, W2, b2, W3, b3, out);
  }
}

// Round 5
// 296.793 us; speedup vs baseline: 1.1290x; 1.1290x over previous
//
#include <hip/hip_runtime.h>

#define E_EDGES 1000000
#define NNODES  100000
#define HID     128
#define NG      31250     // 32-edge groups, exact
#define NBLK    768       // 3 blocks/CU x 256 CUs (LDS-capped at 3: 48 KB/block)

typedef float f32x4 __attribute__((ext_vector_type(4)));
typedef short s16x8 __attribute__((ext_vector_type(8)));

typedef __attribute__((address_space(3))) unsigned int lds_u32;
typedef const __attribute__((address_space(1))) unsigned int glb_u32;

// async 16B/lane global->LDS gather: per-lane global addr, wave-uniform LDS
// base + lane*16 (m104/m108 semantics). Completion tracked by vmcnt; the
// compiler's vmcnt(0)-before-s_barrier makes barrier-delimited use safe.
__device__ __forceinline__ void gl_lds16(const void* g, void* l) {
  __builtin_amdgcn_global_load_lds((glb_u32*)g, (lds_u32*)l, 16, 0, 0);
}

// float -> bf16, round-to-nearest-even (inputs are finite)
__device__ __forceinline__ unsigned short f2bf(float f) {
  unsigned int u = __float_as_uint(f);
  u += 0x7FFFu + ((u >> 16) & 1u);
  return (unsigned short)(u >> 16);
}

__device__ __forceinline__ int4 pack8(float4 a, float4 b) {
  int4 v;
  v.x = (int)((unsigned)f2bf(a.x) | ((unsigned)f2bf(a.y) << 16));
  v.y = (int)((unsigned)f2bf(a.z) | ((unsigned)f2bf(a.w) << 16));
  v.z = (int)((unsigned)f2bf(b.x) | ((unsigned)f2bf(b.y) << 16));
  v.w = (int)((unsigned)f2bf(b.z) | ((unsigned)f2bf(b.w) << 16));
  return v;
}

// x fp32 [NNODES*HID] -> bf16 in ws.
__global__ void cast_x_kernel(const float* __restrict__ x,
                              unsigned short* __restrict__ xb) {
  int i = blockIdx.x * blockDim.x + threadIdx.x;
  const float4* p = (const float4*)x;
  float4 a = p[2 * i];
  float4 b = p[2 * i + 1];
  int4 v = pack8(a, b);
  ((int4*)xb)[i] = v;
}

// Correct-but-slow insurance path if workspace is too small for bf16 x.
__global__ void edge_naive(const float* __restrict__ x, const int* __restrict__ ei,
                           const float* __restrict__ attr, const float* __restrict__ W1,
                           const float* __restrict__ b1, const float* __restrict__ W2,
                           const float* __restrict__ b2, const float* __restrict__ W3,
                           const float* __restrict__ b3, float* __restrict__ out) {
  const int e = blockIdx.x * blockDim.x + threadIdx.x;
  if (e >= E_EDGES) return;
  const float* xs = x + (size_t)ei[e] * HID;
  const float* xd = x + (size_t)ei[E_EDGES + e] * HID;
  const float a = attr[e];
  float h1[HID];
  for (int n = 0; n < HID; ++n) {
    float s = b1[n] + a * W1[256 * HID + n];
    for (int k = 0; k < HID; ++k)
      s += xs[k] * W1[k * HID + n] + xd[k] * W1[(128 + k) * HID + n];
    h1[n] = fmaxf(s, 0.f);
  }
  float o = b3[0];
  for (int n2 = 0; n2 < 32; ++n2) {
    float s = b2[n2];
    for (int n = 0; n < HID; ++n) s += h1[n] * W2[n * 32 + n2];
    o += fmaxf(s, 0.f) * W3[n2];
  }
  out[e] = 1.f / (1.f + __expf(-o));
}

// Block = 128 threads = 2 waves; group = 32 edges = 2 M-tiles of 16.
// Wave w: owns L1 output cols 64w..64w+63 (B1 in regs, 128 VGPR) and all of
// L2/L3 for tile w. ef staged by global_load_lds DMA (no stage VGPRs/LDS-writes),
// double-buffered; h1 double-buffered; ONE barrier per group.
// ef layout: [tile t][side sd][row m][chunk c'] 16B chunks, c' = c ^ (m&7)
//   (XOR applied on the GLOBAL side so DMA's linear lane*16 deposit lands
//    swizzled; A-reads at l15*256 stride then spread across banks, 2-way max).
// h1 k-dim is PERMUTED: value for col n=(w*64+th*16+l15) stored at
//   p = w*64+l15*4+th  =>  writer packs th=0..3 into one ds_write_b64;
//   B2 fragments are built with the same permutation (dot order-invariant).
__launch_bounds__(128, 2)
__global__ void edge_mlp_kernel(const unsigned short* __restrict__ xb,
                                const int* __restrict__ ei,
                                const float* __restrict__ attr,
                                const float* __restrict__ W1,
                                const float* __restrict__ b1,
                                const float* __restrict__ W2,
                                const float* __restrict__ b2,
                                const float* __restrict__ W3,
                                const float* __restrict__ b3,
                                float* __restrict__ out) {
  __shared__ __align__(16) unsigned char ef[2][16384];   // 32 KB
  __shared__ __align__(16) unsigned char h1b[2][8192];   // 16 KB

  const int tid  = threadIdx.x;
  const int w    = tid >> 6;
  const int lane = tid & 63;
  const int q    = lane >> 4;
  const int l15  = lane & 15;

  // ---- L1 weights: wave w owns cols w*64 .. w*64+63 ----
  s16x8 B1[4][8];
  float b1v[4], w1l[4];
#pragma unroll
  for (int th = 0; th < 4; ++th) {
    const int nc = w * 64 + th * 16 + l15;
#pragma unroll
    for (int s = 0; s < 8; ++s)
#pragma unroll
      for (int j = 0; j < 8; ++j)
        B1[th][s][j] = (short)f2bf(W1[(s * 32 + q * 8 + j) * HID + nc]);
    b1v[th] = b1[nc];
    w1l[th] = W1[256 * HID + nc];   // attr column (k=256)
  }
  // ---- L2 weights: wave w -> tile w, both 16-col halves; k permuted ----
  s16x8 B2[2][4];
#pragma unroll
  for (int h = 0; h < 2; ++h) {
    const int n2 = h * 16 + l15;
#pragma unroll
    for (int s2 = 0; s2 < 4; ++s2)
#pragma unroll
      for (int j = 0; j < 8; ++j) {
        const int p = s2 * 32 + q * 8 + j;                     // permuted k
        const int n = (p >> 6) * 64 + (p & 3) * 16 + ((p >> 2) & 15);
        B2[h][s2][j] = (short)f2bf(W2[n * 32 + n2]);
      }
  }
  const float b2v0 = b2[l15],      w3v0 = W3[l15];
  const float b2v1 = b2[16 + l15], w3v1 = W3[16 + l15];
  const float b3v  = b3[0];

  const int bx = blockIdx.x;
  int nid[8];

  // node-id loads for group g (wave w = tile w; i: sd = i>>2, mrow-block = i&3)
  auto load_nid = [&](int g) {
    const int base = g * 32;
#pragma unroll
    for (int i = 0; i < 8; ++i)
      nid[i] = ei[(i >> 2) * E_EDGES + base + w * 16 + (i & 3) * 4 + q];
  };
  // DMA-stage group (uses current nid) into ef[buf]
  auto stage = [&](int buf) {
#pragma unroll
    for (int i = 0; i < 8; ++i) {
      const int m = (i & 3) * 4 + q;
      const unsigned short* gp = xb + (size_t)nid[i] * HID + ((l15 ^ (m & 7)) << 3);
      gl_lds16(gp, &ef[buf][w * 8192 + (i >> 2) * 4096 + (i & 3) * 1024]);
    }
  };

  // ---- prologue ----
  load_nid(bx);
  stage(0);
  if (bx + NBLK < NG) load_nid(bx + NBLK);
  __syncthreads();   // drains DMA(g0)

  const int niter = (NG - bx + NBLK - 1) / NBLK;   // groups this block owns
  for (int it = 0; it <= niter; ++it) {
    const int g   = bx + it * NBLK;     // L1 group
    const int gm  = g - NBLK;           // L2 group (drain at it=niter)
    const int gn  = g + NBLK;           // stage group
    const int cur = it & 1, nxt = cur ^ 1;

    // async prefetch next group (nid loaded last epoch); completes by barrier
    if (gn < NG) stage(nxt);
    // ids two groups ahead (issued early; drained at barrier anyway)
    if (gn + NBLK < NG) load_nid(gn + NBLK);

    // ---- layer 1: ef[cur] -> h1b[cur] ----
    if (g < NG) {
      const float* ap = attr + g * 32;
      const float4 a0 = *(const float4*)(ap + q * 4);
      const float4 a1 = *(const float4*)(ap + 16 + q * 4);
#pragma unroll
      for (int t = 0; t < 2; ++t) {
        f32x4 acc[4] = {{0.f,0.f,0.f,0.f},{0.f,0.f,0.f,0.f},
                        {0.f,0.f,0.f,0.f},{0.f,0.f,0.f,0.f}};
#pragma unroll
        for (int s = 0; s < 8; ++s) {
          const int ch = s * 4 + q;
          const s16x8 A = *(const s16x8*)&ef[cur]
              [t * 8192 + (ch >> 4) * 4096 + l15 * 256 + (((ch & 15) ^ (l15 & 7)) << 4)];
#pragma unroll
          for (int th = 0; th < 4; ++th)
            acc[th] = __builtin_amdgcn_mfma_f32_16x16x32_bf16(A, B1[th][s], acc[th], 0, 0, 0);
        }
        const float4 at = t ? a1 : a0;
#pragma unroll
        for (int r = 0; r < 4; ++r) {
          const int m = q * 4 + r;           // D: row = quad*4+reg, col = l15
          const float ar = ((const float*)&at)[r];
          unsigned long long pk = 0;
#pragma unroll
          for (int th = 0; th < 4; ++th) {
            float v = acc[th][r] + b1v[th] + ar * w1l[th];
            v = fmaxf(v, 0.f);
            pk |= (unsigned long long)f2bf(v) << (16 * th);
          }
          const int pc  = w * 8 + (l15 >> 1);
          const int pcs = ((pc ^ (m & 7)) & 7) | (pc & 8);
          *(unsigned long long*)&h1b[cur][t * 4096 + m * 256 + pcs * 16 + (l15 & 1) * 8] = pk;
        }
      }
    }

    // ---- layer 2+3 for previous group: h1b[nxt] -> out (register-only epilogue)
    if (gm >= 0) {
      s16x8 A2[4];
#pragma unroll
      for (int s2 = 0; s2 < 4; ++s2) {
        const int pc  = s2 * 4 + q;
        const int pcs = ((pc ^ (l15 & 7)) & 7) | (pc & 8);
        A2[s2] = *(const s16x8*)&h1b[nxt][w * 4096 + l15 * 256 + pcs * 16];
      }
      f32x4 c0 = {0.f,0.f,0.f,0.f}, c1 = {0.f,0.f,0.f,0.f};
#pragma unroll
      for (int s2 = 0; s2 < 4; ++s2) {
        c0 = __builtin_amdgcn_mfma_f32_16x16x32_bf16(A2[s2], B2[0][s2], c0, 0, 0, 0);
        c1 = __builtin_amdgcn_mfma_f32_16x16x32_bf16(A2[s2], B2[1][s2], c1, 0, 0, 0);
      }
      float p[4];
#pragma unroll
      for (int r = 0; r < 4; ++r)
        p[r] = fmaxf(c0[r] + b2v0, 0.f) * w3v0 + fmaxf(c1[r] + b2v1, 0.f) * w3v1;
#pragma unroll
      for (int off = 8; off >= 1; off >>= 1)
#pragma unroll
        for (int r = 0; r < 4; ++r)
          p[r] += __shfl_xor(p[r], off, 16);
      if (l15 == 0) {
        float4 o;
#pragma unroll
        for (int r = 0; r < 4; ++r)
          ((float*)&o)[r] = 1.f / (1.f + __expf(-(p[r] + b3v)));
        *(float4*)(out + gm * 32 + w * 16 + q * 4) = o;   // edges m=q*4+r of tile w
      }
    }

    __syncthreads();   // ends epoch: drains DMA(gn), publishes h1b[cur]
  }
}

extern "C" void kernel_launch(void* const* d_in, const int* in_sizes, int n_in,
                              void* d_out, int out_size, void* d_ws, size_t ws_size,
                              hipStream_t stream) {
  const float* x    = (const float*)d_in[0];
  const int*   ei   = (const int*)d_in[1];
  const float* attr = (const float*)d_in[2];
  const float* W1   = (const float*)d_in[3];
  const float* b1   = (const float*)d_in[4];
  const float* W2   = (const float*)d_in[5];
  const float* b2   = (const float*)d_in[6];
  const float* W3   = (const float*)d_in[7];
  const float* b3   = (const float*)d_in[8];
  float* out = (float*)d_out;

  const size_t need = (size_t)NNODES * HID * sizeof(unsigned short);  // 25.6 MB
  if (ws_size >= need) {
    unsigned short* xb = (unsigned short*)d_ws;
    cast_x_kernel<<<6250, 256, 0, stream>>>(x, xb);
    edge_mlp_kernel<<<NBLK, 128, 0, stream>>>(xb, ei, attr, W1, b1, W2, b2, W3, b3, out);
  } else {
    edge_naive<<<(E_EDGES + 255) / 256, 256, 0, stream>>>(x, ei, attr, W1, b1, W2, b2, W3, b3, out);
  }
}